// Round 6
// baseline (379.431 us; speedup 1.0000x reference)
//
#include <hip/hip_runtime.h>
#include <stdint.h>

#define SEQ   2048
#define HID   2048
#define NH    16
#define HD    128
#define BATCH 2

typedef unsigned short u16;
typedef unsigned int   u32;
typedef __attribute__((ext_vector_type(8)))  __bf16 bf16x8;
typedef __attribute__((ext_vector_type(4)))  __bf16 bf16x4;
typedef __attribute__((ext_vector_type(4)))  float  f32x4;
typedef __attribute__((ext_vector_type(16))) float  f32x16;

__device__ __forceinline__ u16 f2bf(float f) {
  union { float f; unsigned int u; } c; c.f = f;
  unsigned int u = c.u;
  return (u16)((u + 0x7fffu + ((u >> 16) & 1u)) >> 16);   // RNE
}

// async global->LDS, 16B/lane. HW writes wave-uniform LDS base + lane*16.
__device__ __forceinline__ void async_ld16(const void* g, void* s) {
  using gptr_t = const __attribute__((address_space(1))) char*;
  using sptr_t = __attribute__((address_space(3))) char*;
  __builtin_amdgcn_global_load_lds((gptr_t)(uintptr_t)g, (sptr_t)(uintptr_t)s, 16, 0, 0);
}

#if __has_builtin(__builtin_amdgcn_permlane32_swap)
__device__ __forceinline__ void plswap(u32& a, u32& b) {
  typedef __attribute__((ext_vector_type(2))) unsigned int u32x2;
  u32x2 r = __builtin_amdgcn_permlane32_swap(a, b, false, false);
  a = r[0]; b = r[1];
}
#else
__device__ __forceinline__ void plswap(u32& a, u32& b) {
  const int hi = (threadIdx.x & 63) >> 5;
  u32 sa = (u32)__shfl_xor((int)a, 32);
  u32 sb = (u32)__shfl_xor((int)b, 32);
  u32 na = hi ? sb : a;
  u32 nb = hi ? b  : sa;
  a = na; b = nb;
}
#endif

// ---------------------------------------------------------------- fused casts + rope tables
__global__ void __launch_bounds__(256) cast5_kernel(
    const float* __restrict__ X,  const float* __restrict__ Wq,
    const float* __restrict__ Wk, const float* __restrict__ Wv,
    const float* __restrict__ Wo,
    u16* __restrict__ Xb, u16* __restrict__ Wqb, u16* __restrict__ Wkb,
    u16* __restrict__ Wvb, u16* __restrict__ Wob,
    float* __restrict__ cosT, float* __restrict__ sinT) {
  const int seg = blockIdx.y;
  const int idx = blockIdx.x * 256 + threadIdx.x;
  if (seg == 5) {
    if (idx >= SEQ * 64 / 4) return;
    const int s = idx >> 4, i0 = (idx & 15) * 4;
    float4 c, sn;
    float* cp = &c.x; float* sp = &sn.x;
#pragma unroll
    for (int e = 0; e < 4; ++e) {
      const float inv = exp2f(-(float)(i0 + e) * 0.20762050593045702f);  // log2(1e4)/64
      const float ang = (float)s * inv;
      cp[e] = cosf(ang); sp[e] = sinf(ang);
    }
    ((float4*)cosT)[idx] = c;
    ((float4*)sinT)[idx] = sn;
    return;
  }
  const float* in = (seg == 0) ? X : (seg == 1) ? Wq : (seg == 2) ? Wk : (seg == 3) ? Wv : Wo;
  u16* out = (seg == 0) ? Xb : (seg == 1) ? Wqb : (seg == 2) ? Wkb : (seg == 3) ? Wvb : Wob;
  const int n4 = (seg == 0) ? (BATCH * SEQ * HID / 4) : (HID * HID / 4);
  if (idx >= n4) return;
  const float4 v = ((const float4*)in)[idx];
  union { u16 us[4]; uint2 u2; } o;
  o.us[0] = f2bf(v.x); o.us[1] = f2bf(v.y); o.us[2] = f2bf(v.z); o.us[3] = f2bf(v.w);
  ((uint2*)out)[idx] = o.u2;
}

// ---------------------------------------------------------------- QKV GEMM, block 128x256, wave 64x128
// C[m,n] = sum_k A[m,k]*W[n,k]. MFMA operand-swapped => acc = C^T (col=m=fr, row=n=fq*4+r).
// z=0/1: Q/K + fused RoPE -> [B,NH,S,HD] bf16. z=2: V -> Vt [B,NH,HD,S].
__global__ void __launch_bounds__(256, 2) gemm_qkv_kernel(
    const u16* __restrict__ A,
    const u16* __restrict__ B0, const u16* __restrict__ B1, const u16* __restrict__ B2,
    u16* __restrict__ Oq, u16* __restrict__ Ok, u16* __restrict__ Ovt,
    const float* __restrict__ cosT, const float* __restrict__ sinT) {
  const int z = blockIdx.z;
  const u16* Bw = (z == 0) ? B0 : (z == 1) ? B1 : B2;

  constexpr int Kd = HID;
  __shared__ __align__(16) char smem[49152];
  char* sAc = smem;            // 128 rows x 128B
  char* sBc = smem + 16384;    // 256 rows x 128B
  const int tid = threadIdx.x;
  const int w = tid >> 6, lane = tid & 63;
  const int wr = w >> 1, wc = w & 1;
  const int m0 = blockIdx.y * 128, n0 = blockIdx.x * 256;
  const int fr = lane & 15, fq = lane >> 4;
  const int srow = lane >> 3;          // 0..7
  const int sup  = lane & 7;

  f32x4 acc[4][8] = {};

  for (int kt = 0; kt < Kd / 64; ++kt) {
    const int k0 = kt * 64;
#pragma unroll
    for (int b2 = 0; b2 < 4; ++b2) {
      const int row = w * 32 + b2 * 8 + srow;
      const int ul = sup ^ (row & 7);
      async_ld16(A + (size_t)(m0 + row) * Kd + k0 + ul * 8, sAc + w * 4096 + b2 * 1024);
    }
#pragma unroll
    for (int b2 = 0; b2 < 8; ++b2) {
      const int row = w * 64 + b2 * 8 + srow;
      const int ul = sup ^ (row & 7);
      async_ld16(Bw + (size_t)(n0 + row) * Kd + k0 + ul * 8, sBc + w * 8192 + b2 * 1024);
    }
    __syncthreads();
#pragma unroll
    for (int kc = 0; kc < 2; ++kc) {
      bf16x8 af[4], bfr[8];
#pragma unroll
      for (int i = 0; i < 4; ++i) {
        const int m = wr * 64 + i * 16 + fr;
        af[i] = *(const bf16x8*)(sAc + m * 128 + ((kc * 4 + fq) ^ (m & 7)) * 16);
      }
#pragma unroll
      for (int j = 0; j < 8; ++j) {
        const int n = wc * 128 + j * 16 + fr;
        bfr[j] = *(const bf16x8*)(sBc + n * 128 + ((kc * 4 + fq) ^ (n & 7)) * 16);
      }
#pragma unroll
      for (int i = 0; i < 4; ++i)
#pragma unroll
        for (int j = 0; j < 8; ++j)
          acc[i][j] = __builtin_amdgcn_mfma_f32_16x16x32_bf16(bfr[j], af[i], acc[i][j], 0, 0, 0);
    }
    __syncthreads();
  }

  const int hbase = n0 >> 7;   // two heads per block (256 cols)
  if (z < 2) {
    u16* Og = (z == 0) ? Oq : Ok;
#pragma unroll
    for (int p = 0; p < 2; ++p) {
      if (wc == p) {
        // stage this col-half: packed C [m][nb], pitch 256B, 16B-unit swizzle ^(m&15)
#pragma unroll
        for (int i = 0; i < 4; ++i)
#pragma unroll
          for (int j = 0; j < 8; ++j) {
            const int m = wr * 64 + i * 16 + fr;
            const int nb = j * 16 + fq * 4;
            union { bf16x4 v; uint2 u; } cv;
            cv.v = __builtin_convertvector(acc[i][j], bf16x4);
            *(uint2*)(smem + m * 256 + (((nb >> 3) ^ (m & 15)) * 16) + (nb & 7) * 2) = cv.u;
          }
      }
      __syncthreads();
#pragma unroll
      for (int rr = 0; rr < 8; ++rr) {
        const int row = rr * 16 + (tid >> 4);
        const int nb = (tid & 15) * 8;
        const int i0 = nb & 63;
        const bf16x8 x  = *(const bf16x8*)(smem + row * 256 + (((nb >> 3) ^ (row & 15)) * 16));
        const bf16x8 xp = *(const bf16x8*)(smem + row * 256 + ((((nb ^ 64) >> 3) ^ (row & 15)) * 16));
        const int mg = m0 + row;
        const int s = mg & (SEQ - 1), b = mg >> 11;
        const float4 c0 = *(const float4*)(cosT + s * 64 + i0);
        const float4 c1 = *(const float4*)(cosT + s * 64 + i0 + 4);
        const float4 s0 = *(const float4*)(sinT + s * 64 + i0);
        const float4 s1 = *(const float4*)(sinT + s * 64 + i0 + 4);
        const float cs[8] = {c0.x, c0.y, c0.z, c0.w, c1.x, c1.y, c1.z, c1.w};
        const float sn[8] = {s0.x, s0.y, s0.z, s0.w, s1.x, s1.y, s1.z, s1.w};
        const float sgn = (nb < 64) ? -1.f : 1.f;
        union { bf16x8 v; uint4 u; } o;
#pragma unroll
        for (int e = 0; e < 8; ++e)
          o.v[e] = (__bf16)((float)x[e] * cs[e] + sgn * (float)xp[e] * sn[e]);
        *(uint4*)(Og + (((size_t)(b * NH + hbase + p) * SEQ + s) << 7) + nb) = o.u;
      }
      __syncthreads();
    }
  } else {
#pragma unroll
    for (int p = 0; p < 2; ++p) {
      if (wc == p) {
        // stage C^T [d][m] scalar for this half
#pragma unroll
        for (int i = 0; i < 4; ++i)
#pragma unroll
          for (int j = 0; j < 8; ++j)
#pragma unroll
            for (int r = 0; r < 4; ++r) {
              const int m = wr * 64 + i * 16 + fr;
              const int dl = j * 16 + fq * 4 + r;
              *(u16*)(smem + dl * 256 + (((m >> 3) ^ (dl & 15)) * 16) + (m & 7) * 2) =
                  f2bf(acc[i][j][r]);
            }
      }
      __syncthreads();
#pragma unroll
      for (int rr = 0; rr < 8; ++rr) {
        const int dl = rr * 16 + (tid >> 4);
        const int mb = (tid & 15) * 8;
        const uint4 v = *(const uint4*)(smem + dl * 256 + (((mb >> 3) ^ (dl & 15)) * 16));
        const int mg = m0 + mb;
        const int s = mg & (SEQ - 1), b = mg >> 11;
        *(uint4*)(Ovt + (((size_t)((b * NH + hbase + p) * HD + dl)) << 11) + s) = v;
      }
      __syncthreads();
    }
  }
}

// ---------------------------------------------------------------- output GEMM, block 128x128, wave 64x64
// acc un-swapped => C (row=m=fq*4+r, col=n=fr): fp32 stores coalesce along n.
__global__ void __launch_bounds__(256) gemm_out_kernel(
    const u16* __restrict__ A, const u16* __restrict__ Bw, float* __restrict__ O) {
  constexpr int Kd = HID;
  __shared__ __align__(16) char smem[32768];
  char* sAc = smem;
  char* sBc = smem + 16384;
  const int tid = threadIdx.x;
  const int w = tid >> 6, lane = tid & 63;
  const int wr = w >> 1, wc = w & 1;
  const int m0 = blockIdx.y * 128, n0 = blockIdx.x * 128;
  const int fr = lane & 15, fq = lane >> 4;
  const int srow = lane >> 3;
  const int sup  = lane & 7;

  f32x4 acc[4][4] = {};

  for (int kt = 0; kt < Kd / 64; ++kt) {
    const int k0 = kt * 64;
#pragma unroll
    for (int b2 = 0; b2 < 4; ++b2) {
      const int row = w * 32 + b2 * 8 + srow;
      const int ul = sup ^ (row & 7);
      async_ld16(A + (size_t)(m0 + row) * Kd + k0 + ul * 8, sAc + w * 4096 + b2 * 1024);
      async_ld16(Bw + (size_t)(n0 + row) * Kd + k0 + ul * 8, sBc + w * 4096 + b2 * 1024);
    }
    __syncthreads();
    bf16x8 af[2][4], bfr[2][4];
#pragma unroll
    for (int kc = 0; kc < 2; ++kc) {
#pragma unroll
      for (int i = 0; i < 4; ++i) {
        const int m = wr * 64 + i * 16 + fr;
        af[kc][i] = *(const bf16x8*)(sAc + m * 128 + ((kc * 4 + fq) ^ (m & 7)) * 16);
        const int n = wc * 64 + i * 16 + fr;
        bfr[kc][i] = *(const bf16x8*)(sBc + n * 128 + ((kc * 4 + fq) ^ (n & 7)) * 16);
      }
    }
#pragma unroll
    for (int kc = 0; kc < 2; ++kc)
#pragma unroll
      for (int i = 0; i < 4; ++i)
#pragma unroll
        for (int j = 0; j < 4; ++j)
          acc[i][j] = __builtin_amdgcn_mfma_f32_16x16x32_bf16(af[kc][i], bfr[kc][j], acc[i][j], 0, 0, 0);
    __syncthreads();
  }

#pragma unroll
  for (int i = 0; i < 4; ++i)
#pragma unroll
    for (int j = 0; j < 4; ++j)
#pragma unroll
      for (int r = 0; r < 4; ++r) {
        const int m = m0 + wr * 64 + i * 16 + fq * 4 + r;
        const int n = n0 + wc * 64 + j * 16 + fr;
        O[(size_t)m * HID + n] = acc[i][j][r];
      }
}

// ---------------------------------------------------------------- flash attention, 32x32x16 MFMA
// BlockQ=128 (4 waves x 32q), 64 keys/kt. S^T = K*Q^T; O^T = Vt*P^T.
__global__ void __launch_bounds__(256, 2) attn_kernel(const u16* __restrict__ Qg,
                                                      const u16* __restrict__ Kg,
                                                      const u16* __restrict__ Vtg,
                                                      u16* __restrict__ Ctx) {
  __shared__ __align__(16) char smem[32768];
  char* sV = smem + 16384;

  const int qt = blockIdx.x, bh = blockIdx.y;
  const int b = bh >> 4, h = bh & (NH - 1);
  const int tid = threadIdx.x, w = tid >> 6, lane = tid & 63;
  const int ml = lane & 31, hi = lane >> 5;

  const u16* Kbase = Kg  + (size_t)bh * SEQ * HD;
  const u16* Vbase = Vtg + (size_t)bh * HD * SEQ;
  const u16* Qbase = Qg  + (size_t)bh * SEQ * HD;

  {
    const int r4 = lane >> 4;
    const int up = lane & 15;
#pragma unroll
    for (int blk = 0; blk < 8; ++blk) {
      const int row = w * 32 + blk * 4 + r4;
      const int ul = up ^ (row & 15);
      async_ld16(Qbase + (size_t)(qt * 128 + row) * HD + ul * 8, smem + w * 8192 + blk * 1024);
    }
  }
  __syncthreads();
  const int qrow = w * 32 + ml;
  bf16x8 qf[8];
#pragma unroll
  for (int kc = 0; kc < 8; ++kc)
    qf[kc] = *(const bf16x8*)(smem + qrow * 256 + (((kc * 2 + hi) ^ (qrow & 15)) * 16));

  f32x16 acco[4] = {};
  float m_run = -1e30f, l_run = 0.f;
  const float scale2 = (float)(1.4426950408889634 / 11.313708498984761);  // log2(e)/sqrt(128)

  for (int kt = 0; kt < SEQ / 64; ++kt) {
    __syncthreads();
    {
      const int r4 = lane >> 4, up16 = lane & 15;
#pragma unroll
      for (int blk = 0; blk < 4; ++blk) {
        const int row = w * 16 + blk * 4 + r4;
        const int ul = up16 ^ (row & 15);
        async_ld16(Kbase + (size_t)(kt * 64 + row) * HD + ul * 8, smem + w * 4096 + blk * 1024);
      }
      const int r8 = lane >> 3, up8 = lane & 7;
#pragma unroll
      for (int blk = 0; blk < 4; ++blk) {
        const int d = w * 32 + blk * 8 + r8;
        const int ul = up8 ^ (d & 7);
        async_ld16(Vbase + (size_t)d * SEQ + kt * 64 + ul * 8, sV + w * 4096 + blk * 1024);
      }
    }
    __syncthreads();

    f32x16 accs[2] = {};
#pragma unroll
    for (int t = 0; t < 2; ++t) {
      const int row = t * 32 + ml;
#pragma unroll
      for (int kc = 0; kc < 8; ++kc) {
        const bf16x8 kf = *(const bf16x8*)(smem + row * 256 + (((kc * 2 + hi) ^ (row & 15)) * 16));
        accs[t] = __builtin_amdgcn_mfma_f32_32x32x16_bf16(kf, qf[kc], accs[t], 0, 0, 0);
      }
    }

    accs[0] *= scale2;
    accs[1] *= scale2;
    const f32x16 mm = __builtin_elementwise_max(accs[0], accs[1]);
    float mx = mm[0];
#pragma unroll
    for (int i = 1; i < 16; ++i) mx = fmaxf(mx, mm[i]);
    mx = fmaxf(mx, __shfl_xor(mx, 32));
    const float mnew = fmaxf(m_run, mx);
    const float alpha = __builtin_amdgcn_exp2f(m_run - mnew);
    m_run = mnew;
    float rs = 0.f;
#pragma unroll
    for (int t = 0; t < 2; ++t)
#pragma unroll
      for (int i = 0; i < 16; ++i) {
        accs[t][i] = __builtin_amdgcn_exp2f(accs[t][i] - mnew);
        rs += accs[t][i];
      }
    rs += __shfl_xor(rs, 32);
    l_run = l_run * alpha + rs;
#pragma unroll
    for (int dt = 0; dt < 4; ++dt) acco[dt] *= alpha;

    u32 pk[2][4][2];
#pragma unroll
    for (int t = 0; t < 2; ++t)
#pragma unroll
      for (int g = 0; g < 4; ++g) {
        const f32x4 gv = {accs[t][4 * g], accs[t][4 * g + 1], accs[t][4 * g + 2], accs[t][4 * g + 3]};
        union { bf16x4 v; u32 u[2]; } cv; cv.v = __builtin_convertvector(gv, bf16x4);
        pk[t][g][0] = cv.u[0]; pk[t][g][1] = cv.u[1];
      }
    bf16x8 pf[4];
#pragma unroll
    for (int kc = 0; kc < 4; ++kc) {
      const int t = kc >> 1, g0 = (kc & 1) * 2;
      u32 a0 = pk[t][g0][0], a1 = pk[t][g0][1];
      u32 b0 = pk[t][g0 + 1][0], b1 = pk[t][g0 + 1][1];
      plswap(a0, b0); plswap(a1, b1);
      union { u32 u[4]; bf16x8 v; } fu;
      fu.u[0] = a0; fu.u[1] = a1; fu.u[2] = b0; fu.u[3] = b1;
      pf[kc] = fu.v;
    }

#pragma unroll
    for (int dt = 0; dt < 4; ++dt) {
      const int d = dt * 32 + ml;
#pragma unroll
      for (int kc = 0; kc < 4; ++kc) {
        const bf16x8 vf = *(const bf16x8*)(sV + d * 128 + (((kc * 2 + hi) ^ (d & 7)) * 16));
        acco[dt] = __builtin_amdgcn_mfma_f32_32x32x16_bf16(vf, pf[kc], acco[dt], 0, 0, 0);
      }
    }
  }

  __syncthreads();
  const float rcp = 1.f / l_run;
  char* ep = smem + w * 8192;
#pragma unroll
  for (int dt = 0; dt < 4; ++dt) {
#pragma unroll
    for (int g = 0; g < 4; ++g) {
      const f32x4 gv = {acco[dt][4 * g] * rcp, acco[dt][4 * g + 1] * rcp,
                        acco[dt][4 * g + 2] * rcp, acco[dt][4 * g + 3] * rcp};
      union { bf16x4 v; uint2 u2; } cv; cv.v = __builtin_convertvector(gv, bf16x4);
      const int ul = dt * 4 + g;
      *(uint2*)(ep + ml * 256 + ((ul ^ (ml & 15)) * 16) + hi * 8) = cv.u2;
    }
  }
  __syncthreads();
#pragma unroll
  for (int rr = 0; rr < 8; ++rr) {
    const int id = rr * 64 + lane;
    const int qv = id >> 4, ul = id & 15;
    const uint4 v = *(const uint4*)(ep + qv * 256 + ((ul ^ (qv & 15)) * 16));
    *(uint4*)(Ctx + (size_t)(b * SEQ + qt * 128 + w * 32 + qv) * HID + h * HD + ul * 8) = v;
  }
}

// ---------------------------------------------------------------- launcher
extern "C" void kernel_launch(void* const* d_in, const int* in_sizes, int n_in,
                              void* d_out, int out_size, void* d_ws, size_t ws_size,
                              hipStream_t stream) {
  (void)in_sizes; (void)n_in; (void)out_size; (void)ws_size;
  const float* X  = (const float*)d_in[0];
  const float* Wq = (const float*)d_in[1];
  const float* Wk = (const float*)d_in[2];
  const float* Wv = (const float*)d_in[3];
  const float* Wo = (const float*)d_in[4];
  float* out = (float*)d_out;
  char* ws = (char*)d_ws;
  const size_t MB = 1024 * 1024;
  u16* Xb  = (u16*)(ws + 0 * MB);
  u16* Wqb = (u16*)(ws + 16 * MB);
  u16* Wkb = (u16*)(ws + 24 * MB);
  u16* Wvb = (u16*)(ws + 32 * MB);
  u16* Wob = (u16*)(ws + 40 * MB);
  u16* Qb  = (u16*)(ws + 48 * MB);
  u16* Kb  = (u16*)(ws + 64 * MB);
  u16* Vtb = (u16*)(ws + 80 * MB);   // [B,NH,HD,S]
  float* cosT = (float*)(ws + 96 * MB);   // rope tables: dead before attn writes Ctx
  float* sinT = cosT + SEQ * 64;
  u16* Ctx = (u16*)(ws + 96 * MB);

  cast5_kernel<<<dim3(8192, 6), 256, 0, stream>>>(X, Wq, Wk, Wv, Wo,
                                                  Xb, Wqb, Wkb, Wvb, Wob, cosT, sinT);
  gemm_qkv_kernel<<<dim3(HID / 256, (BATCH * SEQ) / 128, 3), 256, 0, stream>>>(
      Xb, Wqb, Wkb, Wvb, Qb, Kb, Vtb, cosT, sinT);
  attn_kernel<<<dim3(SEQ / 128, BATCH * NH), 256, 0, stream>>>(Qb, Kb, Vtb, Ctx);
  gemm_out_kernel<<<dim3(HID / 128, (BATCH * SEQ) / 128), 256, 0, stream>>>(
      Ctx, Wob, out);
}